// Round 1
// baseline (66.796 us; speedup 1.0000x reference)
//
#include <hip/hip_runtime.h>
#include <math.h>

// Problem constants (from reference)
constexpr int kC      = 3;
constexpr int kTIn    = 2048;
constexpr int kR      = 64;
constexpr int kTB     = 128;
constexpr int kWin    = 16;          // kTIn / kTB
constexpr float kAlpha = 10.0f;

constexpr int kSPB     = 4;          // samples per block (one wave each)
constexpr int kThreads = 256;
constexpr int kPooledPerBlock = kSPB * kC * kTB;   // 1536

__global__ __launch_bounds__(kThreads, 8)
void resonator_encoder_kernel(const float* __restrict__ traces,
                              const float* __restrict__ drive_w,
                              const float* __restrict__ drive_b,
                              const float* __restrict__ freq_raw,
                              const float* __restrict__ q_raw,
                              const float* __restrict__ thr_raw,
                              float* __restrict__ out)
{
    __shared__ float pooled[kPooledPerBlock];   // [s][c][tb]

    const int tid = threadIdx.x;
    const long long b0 = (long long)blockIdx.x * kSPB;

    const float4* tr4 = reinterpret_cast<const float4*>(traces);
    const long long base4 = b0 * (long long)(kC * kTIn / 4);  // float4 idx of first sample

    // ---- Phase 1: adaptive_avg_pool1d (window 16) ----
    // pooled flat q = s*384 + c*128 + tb  covers floats [q*16, q*16+16) of this block's region
    #pragma unroll
    for (int round = 0; round < kPooledPerBlock / kThreads; ++round) {  // 6 rounds
        int q = round * kThreads + tid;
        long long f4 = base4 + (long long)q * 4;
        float4 a = tr4[f4 + 0];
        float4 b = tr4[f4 + 1];
        float4 c = tr4[f4 + 2];
        float4 d = tr4[f4 + 3];
        float sum = ((a.x + a.y) + (a.z + a.w))
                  + ((b.x + b.y) + (b.z + b.w))
                  + ((c.x + c.y) + (c.z + c.w))
                  + ((d.x + d.y) + (d.z + d.w));
        pooled[q] = sum * (1.0f / 16.0f);
    }
    __syncthreads();

    // ---- Phase 2: per-sample scale = max(maxabs(pooled), 1) ----
    const int s    = tid >> 6;   // wave id == sample within block
    const int lane = tid & 63;
    const int sbase = s * (kC * kTB);

    float m = 0.0f;
    #pragma unroll
    for (int k = 0; k < (kC * kTB) / 64; ++k)     // 6 iters
        m = fmaxf(m, fabsf(pooled[sbase + k * 64 + lane]));
    #pragma unroll
    for (int off = 32; off >= 1; off >>= 1)
        m = fmaxf(m, __shfl_xor(m, off, 64));
    const float inv_scale = 1.0f / fmaxf(m, 1.0f);

    // ---- Phase 3: per-resonator parameters (r == lane) ----
    const int r = lane;
    const float w0   = drive_w[r * kC + 0] * inv_scale;
    const float w1   = drive_w[r * kC + 1] * inv_scale;
    const float w2   = drive_w[r * kC + 2] * inv_scale;
    const float bias = drive_b[r];

    const float fr   = freq_raw[r];
    const float freq = 0.03f + 0.17f / (1.0f + expf(-fr));
    const float qf   = 1.5f + log1pf(expf(q_raw[r]));      // softplus
    const float decay = expf(-1.0f / qf);
    const float thr  = 0.35f + 0.75f / (1.0f + expf(-thr_raw[r]));

    const float* p0 = &pooled[sbase];
    const float* p1 = p0 + kTB;
    const float* p2 = p1 + kTB;

    // ---- Phase 4: 128-step resonator scan (LDS broadcast reads) ----
    const float kExpScale = kAlpha * 1.44269504088896f;  // for exp2
    float state = 0.0f, vel = 0.0f, acc = 0.0f;
    #pragma unroll 4
    for (int t = 0; t < kTB; ++t) {
        float cur = bias;
        cur = fmaf(p0[t], w0, cur);
        cur = fmaf(p1[t], w1, cur);
        cur = fmaf(p2[t], w2, cur);
        vel = fmaf(decay, vel, cur);
        vel = fmaf(-freq, state, vel);
        state = fmaf(freq, vel, state);
        // sigmoid(ALPHA*(state-thr)) = 1/(1 + exp2(kExpScale*(thr-state)))
        float e = __builtin_exp2f(kExpScale * (thr - state));
        float spike = 1.0f / (1.0f + e);
        state = fmaf(-spike, thr, state);
        acc += spike;
    }

    out[(b0 + s) * kR + r] = acc * (1.0f / kTB);
}

extern "C" void kernel_launch(void* const* d_in, const int* in_sizes, int n_in,
                              void* d_out, int out_size, void* d_ws, size_t ws_size,
                              hipStream_t stream)
{
    const float* traces   = (const float*)d_in[0];
    const float* drive_w  = (const float*)d_in[1];
    const float* drive_b  = (const float*)d_in[2];
    const float* freq_raw = (const float*)d_in[3];
    const float* q_raw    = (const float*)d_in[4];
    const float* thr_raw  = (const float*)d_in[5];
    float* out = (float*)d_out;

    const int totalB = in_sizes[0] / (kC * kTIn);   // 8192
    const int grid = totalB / kSPB;                 // 2048

    resonator_encoder_kernel<<<grid, kThreads, 0, stream>>>(
        traces, drive_w, drive_b, freq_raw, q_raw, thr_raw, out);
}

// Round 2
// 61.218 us; speedup vs baseline: 1.0911x; 1.0911x over previous
//
#include <hip/hip_runtime.h>
#include <math.h>

// Problem constants (from reference)
constexpr int kC   = 3;
constexpr int kTIn = 2048;
constexpr int kR   = 64;
constexpr int kTB  = 128;
constexpr float kAlpha = 10.0f;
constexpr float kLog2e = 1.44269504088896f;

#ifndef __has_builtin
#define __has_builtin(x) 0
#endif

static __device__ __forceinline__ float fast_rcp(float x) {
#if __has_builtin(__builtin_amdgcn_rcpf)
    return __builtin_amdgcn_rcpf(x);     // v_rcp_f32, ~1 ulp
#else
    return 1.0f / x;
#endif
}

static __device__ __forceinline__ float fast_exp2(float x) {
#if __has_builtin(__builtin_amdgcn_exp2f)
    return __builtin_amdgcn_exp2f(x);    // v_exp_f32
#else
    return __builtin_exp2f(x);
#endif
}

// ---------------------------------------------------------------------------
// Kernel 1: adaptive_avg_pool1d(16) + per-sample max-abs normalize.
// One block per sample. Unit-stride float4 reads: lane i, inst j reads
// float4 (j*256 + tid) -> window w = j*64 + tid/4 is held by the 4 lanes of
// a quad; two quad shfl_xor adds produce the window sum in all 4 lanes.
// ---------------------------------------------------------------------------
__global__ __launch_bounds__(256, 8)
void pool_norm_kernel(const float* __restrict__ traces,
                      float* __restrict__ pooled)   // [B, C*TB] normalized
{
    const int tid = threadIdx.x;
    const long long b = blockIdx.x;
    const float4* tr4 = reinterpret_cast<const float4*>(traces) + b * (kC * kTIn / 4); // 1536

    float win[6];
    #pragma unroll
    for (int j = 0; j < 6; ++j) {
        float4 v = tr4[j * 256 + tid];
        float s = (v.x + v.y) + (v.z + v.w);
        s += __shfl_xor(s, 1, 64);
        s += __shfl_xor(s, 2, 64);
        win[j] = s;                         // window sum (x16 of the mean)
    }

    // block max-abs reduce (on sums; /16 folded in later)
    float m = 0.0f;
    #pragma unroll
    for (int j = 0; j < 6; ++j) m = fmaxf(m, fabsf(win[j]));
    #pragma unroll
    for (int off = 32; off >= 1; off >>= 1)
        m = fmaxf(m, __shfl_xor(m, off, 64));

    __shared__ float red[4];
    const int wave = tid >> 6;
    if ((tid & 63) == 0) red[wave] = m;
    __syncthreads();

    const float mm = fmaxf(fmaxf(red[0], red[1]), fmaxf(red[2], red[3])) * (1.0f / 16.0f);
    const float inv = fast_rcp(fmaxf(mm, 1.0f)) * (1.0f / 16.0f);

    if ((tid & 3) == 0) {
        float* dst = pooled + b * (kC * kTB) + (tid >> 2);
        #pragma unroll
        for (int j = 0; j < 6; ++j) dst[j * 64] = win[j] * inv;  // 64 consecutive floats per j
    }
}

// ---------------------------------------------------------------------------
// Kernel 2: projection + 128-step resonator scan. One wave per sample,
// lane = resonator. Pooled staged in LDS as [t]{c0,c1,c2,pad} so each scan
// step is a single broadcast ds_read_b128 (conflict-free, hidden under VALU).
// ---------------------------------------------------------------------------
__global__ __launch_bounds__(256, 8)
void scan_kernel(const float* __restrict__ pooled,
                 const float* __restrict__ drive_w,
                 const float* __restrict__ drive_b,
                 const float* __restrict__ freq_raw,
                 const float* __restrict__ q_raw,
                 const float* __restrict__ thr_raw,
                 float* __restrict__ out)
{
    __shared__ float sp[4][kTB * 4];   // [wave][t*4 + c], 8 KB/block
    const int tid  = threadIdx.x;
    const int wave = tid >> 6;
    const int lane = tid & 63;
    const long long b = (long long)blockIdx.x * 4 + wave;

    // stage 384 normalized pooled values, transposed to t-major
    const float* src = pooled + b * (kC * kTB);
    #pragma unroll
    for (int k = 0; k < 6; ++k) {
        int idx = k * 64 + lane;          // coalesced read
        int c = idx >> 7, t = idx & 127;
        sp[wave][t * 4 + c] = src[idx];
    }

    // per-resonator parameters (once, libm accuracy)
    const int r = lane;
    const float w0   = drive_w[r * kC + 0];
    const float w1   = drive_w[r * kC + 1];
    const float w2   = drive_w[r * kC + 2];
    const float bias = drive_b[r];
    const float freq  = 0.03f + 0.17f / (1.0f + expf(-freq_raw[r]));
    const float qf    = 1.5f + log1pf(expf(q_raw[r]));
    const float decay = expf(-1.0f / qf);
    const float thr   = 0.35f + 0.75f / (1.0f + expf(-thr_raw[r]));
    const float expScale = kAlpha * kLog2e;
    const float expThr   = expScale * thr;

    __syncthreads();

    const float4* pt = reinterpret_cast<const float4*>(sp[wave]);
    float state = 0.0f, vel = 0.0f, acc = 0.0f;
    #pragma unroll 8
    for (int t = 0; t < kTB; ++t) {
        float4 p = pt[t];                 // broadcast ds_read_b128
        float cur = bias;
        cur = fmaf(p.x, w0, cur);
        cur = fmaf(p.y, w1, cur);
        cur = fmaf(p.z, w2, cur);
        vel = fmaf(decay, vel, cur);
        vel = fmaf(-freq, state, vel);
        state = fmaf(freq, vel, state);
        // sigmoid(ALPHA*(state-thr)) = 1 / (1 + exp2(expScale*(thr-state)))
        float e = fast_exp2(fmaf(-expScale, state, expThr));
        float spike = fast_rcp(1.0f + e);
        state = fmaf(-spike, thr, state);
        acc += spike;
    }

    out[b * kR + r] = acc * (1.0f / kTB);
}

extern "C" void kernel_launch(void* const* d_in, const int* in_sizes, int n_in,
                              void* d_out, int out_size, void* d_ws, size_t ws_size,
                              hipStream_t stream)
{
    const float* traces   = (const float*)d_in[0];
    const float* drive_w  = (const float*)d_in[1];
    const float* drive_b  = (const float*)d_in[2];
    const float* freq_raw = (const float*)d_in[3];
    const float* q_raw    = (const float*)d_in[4];
    const float* thr_raw  = (const float*)d_in[5];
    float* out = (float*)d_out;

    const int totalB = in_sizes[0] / (kC * kTIn);   // 8192
    float* pooled = (float*)d_ws;                   // [B, C*TB] = 12.6 MB scratch

    pool_norm_kernel<<<totalB, 256, 0, stream>>>(traces, pooled);
    scan_kernel<<<totalB / 4, 256, 0, stream>>>(pooled, drive_w, drive_b,
                                                freq_raw, q_raw, thr_raw, out);
}

// Round 3
// 49.009 us; speedup vs baseline: 1.3629x; 1.2491x over previous
//
#include <hip/hip_runtime.h>
#include <math.h>

// Problem constants (from reference)
constexpr int kC   = 3;
constexpr int kTIn = 2048;
constexpr int kR   = 64;
constexpr int kTB  = 128;
constexpr float kAlpha = 10.0f;
constexpr float kLog2e = 1.44269504088896f;

#ifndef __has_builtin
#define __has_builtin(x) 0
#endif

static __device__ __forceinline__ float fast_rcp(float x) {
#if __has_builtin(__builtin_amdgcn_rcpf)
    return __builtin_amdgcn_rcpf(x);     // v_rcp_f32, ~1 ulp
#else
    return 1.0f / x;
#endif
}

static __device__ __forceinline__ float fast_exp2(float x) {
#if __has_builtin(__builtin_amdgcn_exp2f)
    return __builtin_amdgcn_exp2f(x);    // v_exp_f32
#else
    return __builtin_exp2f(x);
#endif
}

// ---------------------------------------------------------------------------
// Tiny precompute: per-resonator transcendental params (libm accuracy), once.
// ws layout: [4][kR] = freq, decay, thr, thrE (= ALPHA*log2e*thr)
// ---------------------------------------------------------------------------
__global__ void param_kernel(const float* __restrict__ freq_raw,
                             const float* __restrict__ q_raw,
                             const float* __restrict__ thr_raw,
                             float* __restrict__ pp)
{
    const int r = threadIdx.x;
    if (r >= kR) return;
    const float freq  = 0.03f + 0.17f / (1.0f + expf(-freq_raw[r]));
    const float qf    = 1.5f + log1pf(expf(q_raw[r]));
    const float decay = expf(-1.0f / qf);
    const float thr   = 0.35f + 0.75f / (1.0f + expf(-thr_raw[r]));
    pp[0 * kR + r] = freq;
    pp[1 * kR + r] = decay;
    pp[2 * kR + r] = thr;
    pp[3 * kR + r] = thr * (kAlpha * kLog2e);
}

// ---------------------------------------------------------------------------
// Fused kernel: 1 sample per 256-thread block, grid = B (4 generations of
// resident blocks -> load bursts of gen g+1 overlap scans of gen g).
//  Phase 1 (all 4 waves): coalesced float4 loads, quad-shfl window sums,
//          transposed LDS write [t]{c0,c1,c2,pad}, block max-abs reduce.
//  Phase 2 (wave 0 only): 128-step resonator scan, lane = resonator.
// ---------------------------------------------------------------------------
__global__ __launch_bounds__(256, 8)
void fused_encoder_kernel(const float* __restrict__ traces,
                          const float* __restrict__ drive_w,
                          const float* __restrict__ drive_b,
                          const float* __restrict__ pp,
                          float* __restrict__ out)
{
    __shared__ float sp[kTB * 4];    // [t*4 + c], c=3 padded to 4 -> 2 KB
    __shared__ float red[4];

    const int tid  = threadIdx.x;
    const int wave = tid >> 6;
    const int lane = tid & 63;
    const long long b = blockIdx.x;

    const float4* tr4 = reinterpret_cast<const float4*>(traces)
                        + b * (kC * kTIn / 4);          // 1536 float4 per sample

    // ---- Phase 1: pool (window=16). float4 j*256+tid is window-quad-aligned:
    // window w = j*64 + (tid>>2); two quad shfl_xor adds -> window sum (x16 mean)
    float win[6];
    #pragma unroll
    for (int j = 0; j < 6; ++j) {
        float4 v = tr4[j * 256 + tid];
        float s = (v.x + v.y) + (v.z + v.w);
        s += __shfl_xor(s, 1, 64);
        s += __shfl_xor(s, 2, 64);
        win[j] = s;
    }

    // transposed LDS write: w = c*128 + t  ->  sp[t*4 + c]
    if ((tid & 3) == 0) {
        const int wq = tid >> 2;
        #pragma unroll
        for (int j = 0; j < 6; ++j) {
            int w = j * 64 + wq;
            sp[(w & 127) * 4 + (w >> 7)] = win[j];
        }
    }

    // block max-abs of window sums
    float m = 0.0f;
    #pragma unroll
    for (int j = 0; j < 6; ++j) m = fmaxf(m, fabsf(win[j]));
    #pragma unroll
    for (int off = 32; off >= 1; off >>= 1)
        m = fmaxf(m, __shfl_xor(m, off, 64));
    if (lane == 0) red[wave] = m;
    __syncthreads();

    if (wave != 0) return;   // waves 1-3 done (no further barriers below)

    // ---- Phase 2: wave 0, lane = resonator ----
    const float summax = fmaxf(fmaxf(red[0], red[1]), fmaxf(red[2], red[3]));
    // pooled_norm = (sum/16)/max(summax/16, 1)  -> fold into weights
    const float inv = fast_rcp(fmaxf(summax * (1.0f / 16.0f), 1.0f)) * (1.0f / 16.0f);

    const int r = lane;
    const float w0   = drive_w[r * kC + 0] * inv;
    const float w1   = drive_w[r * kC + 1] * inv;
    const float w2   = drive_w[r * kC + 2] * inv;
    const float bias = drive_b[r];
    const float freq  = pp[0 * kR + r];
    const float decay = pp[1 * kR + r];
    const float thr   = pp[2 * kR + r];
    const float thrE  = pp[3 * kR + r];
    const float expScale = kAlpha * kLog2e;

    const float4* pt = reinterpret_cast<const float4*>(sp);
    float state = 0.0f, vel = 0.0f, acc = 0.0f;
    #pragma unroll 8
    for (int t = 0; t < kTB; ++t) {
        float4 p = pt[t];                 // broadcast ds_read_b128
        float cur = fmaf(p.x, w0, bias);
        cur = fmaf(p.y, w1, cur);
        cur = fmaf(p.z, w2, cur);
        vel = fmaf(decay, vel, cur);
        vel = fmaf(-freq, state, vel);
        state = fmaf(freq, vel, state);
        // sigmoid(ALPHA*(state-thr)) = 1 / (1 + exp2(expScale*thr - expScale*state))
        float e = fast_exp2(fmaf(-expScale, state, thrE));
        float spike = fast_rcp(1.0f + e);
        state = fmaf(-spike, thr, state);
        acc += spike;
    }

    out[b * kR + r] = acc * (1.0f / kTB);
}

extern "C" void kernel_launch(void* const* d_in, const int* in_sizes, int n_in,
                              void* d_out, int out_size, void* d_ws, size_t ws_size,
                              hipStream_t stream)
{
    const float* traces   = (const float*)d_in[0];
    const float* drive_w  = (const float*)d_in[1];
    const float* drive_b  = (const float*)d_in[2];
    const float* freq_raw = (const float*)d_in[3];
    const float* q_raw    = (const float*)d_in[4];
    const float* thr_raw  = (const float*)d_in[5];
    float* out = (float*)d_out;
    float* pp  = (float*)d_ws;                      // [4][kR] precomputed params

    const int totalB = in_sizes[0] / (kC * kTIn);   // 8192

    param_kernel<<<1, 64, 0, stream>>>(freq_raw, q_raw, thr_raw, pp);
    fused_encoder_kernel<<<totalB, 256, 0, stream>>>(traces, drive_w, drive_b, pp, out);
}